// Round 3
// baseline (205.861 us; speedup 1.0000x reference)
//
#include <hip/hip_runtime.h>
#include <math.h>

using bf16x8 = __attribute__((ext_vector_type(8))) __bf16;
using f32x4  = __attribute__((ext_vector_type(4))) float;

#if __has_builtin(__builtin_amdgcn_exp2f)
#define EXP2F(x) __builtin_amdgcn_exp2f(x)
#else
#define EXP2F(x) exp2f(x)
#endif

__device__ __forceinline__ unsigned short f2bf(float f) {
  unsigned u = __float_as_uint(f);
  unsigned r = u + 0x7fffu + ((u >> 16) & 1u);
  return (unsigned short)(r >> 16);
}

// HW packed f32->bf16 (RNE, same rounding as f2bf). No builtin on gfx950 -> asm.
__device__ __forceinline__ unsigned cvt_pk_bf16(float a, float b) {
  unsigned r;
  asm("v_cvt_pk_bf16_f32 %0, %1, %2" : "=v"(r) : "v"(a), "v"(b));
  return r;
}
__device__ __forceinline__ uint2 pk4(float a, float b, float c, float d) {
  uint2 r; r.x = cvt_pk_bf16(a, b); r.y = cvt_pk_bf16(c, d); return r;
}

__device__ __forceinline__ f32x4 mfma16(uint4 a, uint4 b, f32x4 c) {
  return __builtin_amdgcn_mfma_f32_16x16x32_bf16(
      __builtin_bit_cast(bf16x8, a), __builtin_bit_cast(bf16x8, b), c, 0, 0, 0);
}
__device__ __forceinline__ float swz_xor16(float v) {
  return __int_as_float(__builtin_amdgcn_ds_swizzle(__float_as_int(v), 0x401F));
}

// B-fragment swizzled layout for mfma_f32_16x16x32_bf16:
// element (k, n) -> chunk index (((n>>4)*2 + (k>>5))*64 + ((k>>3)&3)*16 + (n&15))*8 + (k&7)
#define FRAG_OFF(k, n) (((((n) >> 4) * 2 + ((k) >> 5)) * 64 + (((k) >> 3) & 3) * 16 + ((n) & 15)) * 8 + ((k) & 7))

// attention score prescale: (1/sqrt(8)) * log2(e) folded into AQ/qb2
#define ATT_C 0.51006997f

// ---------------- precompute: bf16 weights + algebraic folds -> d_ws ----------------
// wsb (ushort): W1[3][4096]@0  W2[3][4096]@12288  PM1A@24576  PM2@28672
//               AQ@32768  AK@36864  AV@40960  MO@45056  OUT@49152
// wsf (float):  Cpat[4096]@0  geoT[4096]@4096  qb2@8192 kb2@8256 vb2@8320
__global__ void precompute_kernel(
    const float* __restrict__ conv1_w, const float* __restrict__ conv2_w,
    const float* __restrict__ pm1_w, const float* __restrict__ pm1_b,
    const float* __restrict__ pm2_w,
    const float* __restrict__ q_w, const float* __restrict__ q_b,
    const float* __restrict__ k_w, const float* __restrict__ k_b,
    const float* __restrict__ v_w, const float* __restrict__ v_b,
    const float* __restrict__ in_w, const float* __restrict__ in_b,
    const float* __restrict__ mo_w, const float* __restrict__ out_w,
    const float* __restrict__ pattern, const float* __restrict__ points,
    const int* __restrict__ adjacency,
    unsigned short* __restrict__ wsb, float* __restrict__ wsf) {
  int idx = blockIdx.x * 256 + threadIdx.x;
  if (idx < 12288) {                       // W1_t[oc][c] = conv1_w[oc][c][t]
    int t = idx >> 12, rem = idx & 4095;
    int oc = rem >> 6, c = rem & 63;
    wsb[idx] = f2bf(conv1_w[(oc * 64 + c) * 3 + t]);
  } else if (idx < 24576) {                // W2_t block-diagonal dense
    int i2 = idx - 12288;
    int t = i2 >> 12, rem = i2 & 4095;
    int oc = rem >> 6, ci = rem & 63;
    float v = ((ci >> 4) == (oc >> 4)) ? conv2_w[(oc * 16 + (ci & 15)) * 3 + t] : 0.0f;
    wsb[idx] = f2bf(v);
  } else if (idx < 28672) {                // PM1A = pm1_w[:, :64]
    int rem = idx - 24576;
    wsb[idx] = f2bf(pm1_w[(rem >> 6) * 80 + (rem & 63)]);
  } else if (idx < 32768) {                // PM2
    wsb[idx] = f2bf(pm2_w[idx - 28672]);
  } else if (idx < 36864) {                // AQ = (wq @ q_w) * ATT_C
    int rem = idx - 32768; int c = rem >> 6, k = rem & 63;
    float s = 0.f;
    #pragma unroll 8
    for (int j = 0; j < 64; ++j) s += in_w[c * 64 + j] * q_w[j * 64 + k];
    wsb[idx] = f2bf(s * ATT_C);
  } else if (idx < 40960) {                // AK = wk @ k_w
    int rem = idx - 36864; int c = rem >> 6, k = rem & 63;
    float s = 0.f;
    #pragma unroll 8
    for (int j = 0; j < 64; ++j) s += in_w[(64 + c) * 64 + j] * k_w[j * 64 + k];
    wsb[idx] = f2bf(s);
  } else if (idx < 45056) {                // AV = wv @ v_w
    int rem = idx - 40960; int c = rem >> 6, k = rem & 63;
    float s = 0.f;
    #pragma unroll 8
    for (int j = 0; j < 64; ++j) s += in_w[(128 + c) * 64 + j] * v_w[j * 64 + k];
    wsb[idx] = f2bf(s);
  } else if (idx < 49152) {                // MO
    wsb[idx] = f2bf(mo_w[idx - 45056]);
  } else if (idx < 53248) {                // OUT
    wsb[idx] = f2bf(out_w[idx - 49152]);
  } else if (idx < 57344) {                // Cpat[c][n] = pm1_w[:,64:] @ pat^T + pm1_b
    int rem = idx - 53248; int c = rem >> 6, n = rem & 63;
    float s = pm1_b[c];
    #pragma unroll
    for (int cp = 0; cp < 16; ++cp) s += pm1_w[c * 80 + 64 + cp] * pattern[n * 16 + cp];
    wsf[rem] = s;
  } else if (idx < 61440) {                // geoT[c][n] = geo[n][c]
    int rem = idx - 57344; int c = rem >> 6, n = rem & 63;
    float dd = 1e-12f;
    #pragma unroll
    for (int i = 0; i < 3; ++i) { float d = points[n * 3 + i] - points[c * 3 + i]; dd += d * d; }
    float dist = sqrtf(dd);
    wsf[4096 + rem] = (adjacency[n * 64 + c] > 0) ? 0.5f : (-0.1f / (1.0f + dist));
  } else if (idx < 61632) {                // fused qkv biases (q scaled by ATT_C)
    int rem = idx - 61440; int which = rem >> 6, c = rem & 63;
    if (which == 0) {
      float s = in_b[c];
      for (int j = 0; j < 64; ++j) s += in_w[c * 64 + j] * q_b[j];
      wsf[8192 + c] = s * ATT_C;
    } else if (which == 1) {
      float s = in_b[64 + c];
      for (int j = 0; j < 64; ++j) s += in_w[(64 + c) * 64 + j] * k_b[j];
      wsf[8256 + c] = s;
    } else {
      float s = in_b[128 + c];
      for (int j = 0; j < 64; ++j) s += in_w[(128 + c) * 64 + j] * v_b[j];
      wsf[8320 + c] = s;
    }
  }
}

// 8-wave split 64x64x64 GEMM: wave (wm,wn) computes rows c in [16wm,16wm+16),
// cols n in [32wn, 32wn+32): acc[2] n-tiles.
__device__ __forceinline__ void gemm64(const unsigned short* __restrict__ Wg,
                                       const unsigned short* Bf,
                                       int wm, int wn, int lane, f32x4 acc[2]) {
  const int l15 = lane & 15, lq = lane >> 4;
  #pragma unroll
  for (int s = 0; s < 2; ++s) {
    bf16x8 a = *reinterpret_cast<const bf16x8*>(Wg + (16 * wm + l15) * 64 + s * 32 + lq * 8);
    #pragma unroll
    for (int nti = 0; nti < 2; ++nti) {
      int nt = 2 * wn + nti;
      bf16x8 bb = *reinterpret_cast<const bf16x8*>(Bf + ((nt * 2 + s) * 64 + lane) * 8);
      acc[nti] = __builtin_amdgcn_mfma_f32_16x16x32_bf16(a, bb, acc[nti], 0, 0, 0);
    }
  }
}

// LDS pool 35840 B (R1 layout, shorts idx unless noted), phase-overlaid:
//  SLOT_A @0     (8KB):  XF(0-1) PIF(2-3) PFF(4-5) CTXF(6-7) HNF(8-9)
//  SLOT_B @4096  (9216B): Y1F(1-2) T1F(3-4) Q[n][72](5-6)
//  KBASE  @8704  (9216B): K[n][72](5-6a) Pscr lower(6b)
//  VBASE  @13312 (9216B): zero-guard(ph1-2) V[c][72](5-6a) Pscr upper(6b) LN scratch(8)
//  Pscr: 8 waves x 1152 shorts spanning KBASE..KBASE+9216 shorts (K+V dead after 6a)
//  H32 f32 idx 2048, stride 65 (7-8): overlays SLOT_B+KBASE (Q,K dead)
#define SLOT_B 4096
#define KBASE  8704
#define VBASE  13312
#define H32F   2048   /* f32 idx */
#define LNS    6656   /* f32 idx */

__global__ __launch_bounds__(512, 8) void fused_kernel(
    const float* __restrict__ x,
    const unsigned short* __restrict__ wsb, const float* __restrict__ wsf,
    const float* __restrict__ conv1_b, const float* __restrict__ conv2_b,
    const float* __restrict__ pm2_b, const float* __restrict__ mo_b,
    const float* __restrict__ out_b, const float* __restrict__ ln_g,
    const float* __restrict__ ln_beta, float* __restrict__ out) {
  __shared__ __align__(16) unsigned char smem_raw[35840];
  unsigned short* S16 = reinterpret_cast<unsigned short*>(smem_raw);
  float* S32 = reinterpret_cast<float*>(smem_raw);

  const int tid = threadIdx.x;
  const int b = blockIdx.x;
  const int lane = tid & 63;
  const int w = tid >> 6;            // 8 waves
  const int wm = w >> 1;             // M-tile [16wm, 16wm+16)
  const int wn = w & 1;              // N-half [32wn, 32wn+32)
  const int l15 = lane & 15;
  const int lq = lane >> 4;
  const int c0 = 16 * wm + lq * 4;   // D-frag row base for this lane
  f32x4 pfs[2];                      // pf residual, D-layout, ph4 -> ph7

  // ---------- Phase 0: zero-guard + stage x -> XF ----------
  // Wave w owns rows c in [8w, 8w+8), column n = lane (coalesced 256B loads).
  if (tid < 8) S16[VBASE + tid] = 0;   // 16B zero chunk for OOB shifted reads
  {
    const float* xb = x + b * 4096 + w * 8 * 64 + lane;
    float v[8];
    #pragma unroll
    for (int j = 0; j < 8; ++j) v[j] = xb[j * 64];
    uint4 u;
    u.x = cvt_pk_bf16(v[0], v[1]);
    u.y = cvt_pk_bf16(v[2], v[3]);
    u.z = cvt_pk_bf16(v[4], v[5]);
    u.w = cvt_pk_bf16(v[6], v[7]);
    *reinterpret_cast<uint4*>(S16 + FRAG_OFF(w * 8, lane)) = u;
  }
  __syncthreads();

  // ---------- conv helper: sum_t W_t @ shift(src, t-1), with zero-guard ----------
  auto conv_pass = [&](const unsigned short* Wg, int srcBase, f32x4 acc[2]) {
    bf16x8 a6[3][2];
    #pragma unroll
    for (int t = 0; t < 3; ++t)
      #pragma unroll
      for (int s = 0; s < 2; ++s)
        a6[t][s] = *reinterpret_cast<const bf16x8*>(Wg + t * 4096 + (16 * wm + l15) * 64 + s * 32 + lq * 8);
    #pragma unroll
    for (int nti = 0; nti < 2; ++nti) {
      int nt = 2 * wn + nti;
      #pragma unroll
      for (int t = 0; t < 3; ++t) {
        int np = nt * 16 + l15 + (t - 1);
        bool ok = (unsigned)np < 64u;
        int a = srcBase + (((np >> 4) * 2) * 64 + lq * 16 + (np & 15)) * 8;
        int A0 = ok ? a : VBASE;
        int A1 = ok ? (a + 512) : VBASE;
        bf16x8 b0 = *reinterpret_cast<const bf16x8*>(S16 + A0);
        bf16x8 b1 = *reinterpret_cast<const bf16x8*>(S16 + A1);
        acc[nti] = __builtin_amdgcn_mfma_f32_16x16x32_bf16(a6[t][0], b0, acc[nti], 0, 0, 0);
        acc[nti] = __builtin_amdgcn_mfma_f32_16x16x32_bf16(a6[t][1], b1, acc[nti], 0, 0, 0);
      }
    }
  };

  // ---------- Phase 1: conv1 -> Y1F @SLOT_B ----------
  {
    f32x4 acc[2] = {};
    conv_pass(wsb, 0, acc);
    float bia[4] = {conv1_b[c0], conv1_b[c0 + 1], conv1_b[c0 + 2], conv1_b[c0 + 3]};
    #pragma unroll
    for (int nti = 0; nti < 2; ++nti) {
      int n = (2 * wn + nti) * 16 + l15;
      uint2 u = pk4(fmaxf(acc[nti][0] + bia[0], 0.f), fmaxf(acc[nti][1] + bia[1], 0.f),
                    fmaxf(acc[nti][2] + bia[2], 0.f), fmaxf(acc[nti][3] + bia[3], 0.f));
      *reinterpret_cast<uint2*>(S16 + SLOT_B + FRAG_OFF(c0, n)) = u;
    }
  }
  __syncthreads();

  // ---------- Phase 2: conv2 -> PIF @SLOT_A ----------
  {
    f32x4 acc[2] = {};
    conv_pass(wsb + 12288, SLOT_B, acc);
    float bia[4] = {conv2_b[c0], conv2_b[c0 + 1], conv2_b[c0 + 2], conv2_b[c0 + 3]};
    #pragma unroll
    for (int nti = 0; nti < 2; ++nti) {
      int n = (2 * wn + nti) * 16 + l15;
      uint2 u = pk4(fmaxf(acc[nti][0] + bia[0], 0.f), fmaxf(acc[nti][1] + bia[1], 0.f),
                    fmaxf(acc[nti][2] + bia[2], 0.f), fmaxf(acc[nti][3] + bia[3], 0.f));
      *reinterpret_cast<uint2*>(S16 + FRAG_OFF(c0, n)) = u;
    }
  }
  __syncthreads();

  // ---------- Phase 3: pm1: relu(PM1A @ PIF + Cpat) -> T1F @SLOT_B ----------
  {
    f32x4 acc[2] = {};
    gemm64(wsb + 24576, S16, wm, wn, lane, acc);
    #pragma unroll
    for (int nti = 0; nti < 2; ++nti) {
      int n = (2 * wn + nti) * 16 + l15;
      uint2 u = pk4(fmaxf(acc[nti][0] + wsf[(c0 + 0) * 64 + n], 0.f),
                    fmaxf(acc[nti][1] + wsf[(c0 + 1) * 64 + n], 0.f),
                    fmaxf(acc[nti][2] + wsf[(c0 + 2) * 64 + n], 0.f),
                    fmaxf(acc[nti][3] + wsf[(c0 + 3) * 64 + n], 0.f));
      *reinterpret_cast<uint2*>(S16 + SLOT_B + FRAG_OFF(c0, n)) = u;
    }
  }
  __syncthreads();

  // ---------- Phase 4: pm2: PM2 @ T1F + b -> PFF @SLOT_A + pf regs ----------
  {
    f32x4 acc[2] = {};
    gemm64(wsb + 28672, S16 + SLOT_B, wm, wn, lane, acc);
    float bia[4] = {pm2_b[c0], pm2_b[c0 + 1], pm2_b[c0 + 2], pm2_b[c0 + 3]};
    #pragma unroll
    for (int nti = 0; nti < 2; ++nti) {
      int n = (2 * wn + nti) * 16 + l15;
      f32x4 v;
      #pragma unroll
      for (int r = 0; r < 4; ++r) v[r] = acc[nti][r] + bia[r];
      pfs[nti] = v;
      *reinterpret_cast<uint2*>(S16 + FRAG_OFF(c0, n)) = pk4(v[0], v[1], v[2], v[3]);
    }
  }
  __syncthreads();

  // ---------- Phase 5: Q@SLOT_B, K@KBASE (bf16 [n][72]); V@VBASE (bf16 [c][72]) ----------
  {
    f32x4 acc[2] = {};
    gemm64(wsb + 32768, S16, wm, wn, lane, acc);   // AQ (pre-scaled)
    #pragma unroll
    for (int nti = 0; nti < 2; ++nti) {
      int n = (2 * wn + nti) * 16 + l15;
      *reinterpret_cast<uint2*>(S16 + SLOT_B + n * 72 + c0) =
          pk4(acc[nti][0] + wsf[8192 + c0], acc[nti][1] + wsf[8192 + c0 + 1],
              acc[nti][2] + wsf[8192 + c0 + 2], acc[nti][3] + wsf[8192 + c0 + 3]);
    }
  }
  {
    f32x4 acc[2] = {};
    gemm64(wsb + 36864, S16, wm, wn, lane, acc);   // AK
    #pragma unroll
    for (int nti = 0; nti < 2; ++nti) {
      int n = (2 * wn + nti) * 16 + l15;
      *reinterpret_cast<uint2*>(S16 + KBASE + n * 72 + c0) =
          pk4(acc[nti][0] + wsf[8256 + c0], acc[nti][1] + wsf[8256 + c0 + 1],
              acc[nti][2] + wsf[8256 + c0 + 2], acc[nti][3] + wsf[8256 + c0 + 3]);
    }
  }
  {
    f32x4 acc[2] = {};
    gemm64(wsb + 40960, S16, wm, wn, lane, acc);   // AV -> [c][72] scatter
    #pragma unroll
    for (int nti = 0; nti < 2; ++nti) {
      int n = (2 * wn + nti) * 16 + l15;
      #pragma unroll
      for (int r = 0; r < 4; ++r)
        S16[VBASE + (c0 + r) * 72 + n] = f2bf(acc[nti][r] + wsf[8320 + c0 + r]);
    }
  }
  __syncthreads();

  // ---------- Phase 6: MFMA attention, one head per wave (h = w) ----------
  {
    const int h = w;
    const bool lq0 = (lq == 0);
    // 6a: preload V B-frags AND K A-frags (Pscr will overlay both K and V)
    uint4 vb[2];
    #pragma unroll
    for (int ks = 0; ks < 2; ++ks)
      vb[ks] = *reinterpret_cast<const uint4*>(
          S16 + VBASE + (h * 8 + (l15 & 7)) * 72 + ks * 32 + lq * 8);
    uint4 ka[4];
    #pragma unroll
    for (int mt = 0; mt < 4; ++mt) {
      uint4 t = *reinterpret_cast<const uint4*>(S16 + KBASE + (mt * 16 + l15) * 72 + h * 8);
      ka[mt].x = lq0 ? t.x : 0u; ka[mt].y = lq0 ? t.y : 0u;
      ka[mt].z = lq0 ? t.z : 0u; ka[mt].w = lq0 ? t.w : 0u;
    }
    __syncthreads();   // all K/V reads done before Pscr overwrites the regions

    const int Pb = KBASE + w * 1152;   // per-wave P scratch (2304B), spans K+V regions
    #pragma unroll
    for (int q = 0; q < 4; ++q) {      // 16-query quarters
      uint4 qb = *reinterpret_cast<const uint4*>(S16 + SLOT_B + (q * 16 + l15) * 72 + h * 8);
      qb.x = lq0 ? qb.x : 0u; qb.y = lq0 ? qb.y : 0u;
      qb.z = lq0 ? qb.z : 0u; qb.w = lq0 ? qb.w : 0u;
      f32x4 sc[4];
      #pragma unroll
      for (int mt = 0; mt < 4; ++mt) {
        f32x4 z = {0.f, 0.f, 0.f, 0.f};
        sc[mt] = mfma16(ka[mt], qb, z);   // S[m][n=l15] in exp2 domain
      }
      // softmax denominator (no max pass; scores are small)
      float sum = 0.f;
      #pragma unroll
      for (int mt = 0; mt < 4; ++mt)
        #pragma unroll
        for (int r = 0; r < 4; ++r) {
          float e = EXP2F(sc[mt][r]);
          sc[mt][r] = e; sum += e;
        }
      sum += swz_xor16(sum);
      sum += __shfl_xor(sum, 32);
      float inv = __builtin_amdgcn_rcpf(sum);
      // normalized P -> bf16 (truncation via v_perm) -> per-wave scratch [n=l15][m]
      #pragma unroll
      for (int mt = 0; mt < 4; ++mt) {
        unsigned d0 = __builtin_amdgcn_perm(__float_as_uint(sc[mt][1] * inv),
                                            __float_as_uint(sc[mt][0] * inv), 0x07060302u);
        unsigned d1 = __builtin_amdgcn_perm(__float_as_uint(sc[mt][3] * inv),
                                            __float_as_uint(sc[mt][2] * inv), 0x07060302u);
        *reinterpret_cast<uint2*>(S16 + Pb + l15 * 72 + mt * 16 + lq * 4) = make_uint2(d0, d1);
      }
      // PV: ctx[n][d] = sum_m P[n][m] V[h*8+d][m]
      f32x4 ctx = {0.f, 0.f, 0.f, 0.f};
      #pragma unroll
      for (int ks = 0; ks < 2; ++ks) {
        uint4 pa = *reinterpret_cast<const uint4*>(S16 + Pb + l15 * 72 + ks * 32 + lq * 8);
        ctx = mfma16(pa, vb[ks], ctx);
      }
      // scatter ctx (C-layout: n=q*16+lq*4+r, d=l15<8) into CTXF @SLOT_A
      if (l15 < 8) {
        const int kk = h * 8 + l15;
        #pragma unroll
        for (int r = 0; r < 4; ++r)
          S16[FRAG_OFF(kk, q * 16 + lq * 4 + r)] = f2bf(ctx[r]);
      }
    }
  }
  __syncthreads();

  // ---------- Phase 7: MO @ CTXF + mo_b + geoT + pf(regs) -> H32 (f32 stride 65) ----------
  {
    f32x4 acc[2] = {};
    gemm64(wsb + 45056, S16, wm, wn, lane, acc);
    #pragma unroll
    for (int nti = 0; nti < 2; ++nti) {
      int n = (2 * wn + nti) * 16 + l15;
      #pragma unroll
      for (int r = 0; r < 4; ++r) {
        int c = c0 + r;
        S32[H32F + c * 65 + n] = acc[nti][r] + mo_b[c] + wsf[4096 + c * 64 + n] + pfs[nti][r];
      }
    }
  }
  __syncthreads();

  // ---------- Phase 8: LayerNorm over channels (per column n) -> HNF @SLOT_A ----------
  {
    int n = tid & 63, qq = tid >> 6;   // qq in [0,8): 8 channels per thread
    float sum = 0.f, ssq = 0.f;
    #pragma unroll
    for (int j = 0; j < 8; ++j) {
      float v = S32[H32F + (qq * 8 + j) * 65 + n];
      sum += v; ssq += v * v;
    }
    S32[LNS + tid] = sum;
    S32[LNS + 512 + tid] = ssq;
    __syncthreads();
    if (tid < 64) {
      float s = 0.f, ss = 0.f;
      #pragma unroll
      for (int i = 0; i < 8; ++i) {
        s  += S32[LNS + i * 64 + tid];
        ss += S32[LNS + 512 + i * 64 + tid];
      }
      float mu = s * (1.0f / 64.0f);
      float var = ss * (1.0f / 64.0f) - mu * mu;
      S32[LNS + 1024 + tid] = mu;
      S32[LNS + 1088 + tid] = rsqrtf(var + 1e-5f);
    }
    __syncthreads();
    float mu = S32[LNS + 1024 + n], rs = S32[LNS + 1088 + n];
    int ch0 = qq * 8;
    float vv[8];
    #pragma unroll
    for (int jj = 0; jj < 8; ++jj) {
      int c = ch0 + jj;
      vv[jj] = (S32[H32F + c * 65 + n] - mu) * rs * ln_g[c] + ln_beta[c];
    }
    uint4 u;
    u.x = cvt_pk_bf16(vv[0], vv[1]);
    u.y = cvt_pk_bf16(vv[2], vv[3]);
    u.z = cvt_pk_bf16(vv[4], vv[5]);
    u.w = cvt_pk_bf16(vv[6], vv[7]);
    *reinterpret_cast<uint4*>(S16 + FRAG_OFF(ch0, n)) = u;
  }
  __syncthreads();

  // ---------- Phase 9: OUT @ HNF + out_b -> global [b][c][n] ----------
  {
    f32x4 acc[2] = {};
    gemm64(wsb + 49152, S16, wm, wn, lane, acc);
    float* ob = out + b * 4096;
    float bia[4] = {out_b[c0], out_b[c0 + 1], out_b[c0 + 2], out_b[c0 + 3]};
    #pragma unroll
    for (int nti = 0; nti < 2; ++nti) {
      int n = (2 * wn + nti) * 16 + l15;
      #pragma unroll
      for (int r = 0; r < 4; ++r)
        ob[(c0 + r) * 64 + n] = acc[nti][r] + bia[r];
    }
  }
}

extern "C" void kernel_launch(void* const* d_in, const int* in_sizes, int n_in,
                              void* d_out, int out_size, void* d_ws, size_t ws_size,
                              hipStream_t stream) {
  const float* x        = (const float*)d_in[0];
  const float* points   = (const float*)d_in[1];
  const float* conv1_w  = (const float*)d_in[2];
  const float* conv1_b  = (const float*)d_in[3];
  const float* conv2_w  = (const float*)d_in[4];
  const float* conv2_b  = (const float*)d_in[5];
  const float* pattern  = (const float*)d_in[6];
  const float* pm1_w    = (const float*)d_in[7];
  const float* pm1_b    = (const float*)d_in[8];
  const float* pm2_w    = (const float*)d_in[9];
  const float* pm2_b    = (const float*)d_in[10];
  const float* q_w      = (const float*)d_in[11];
  const float* q_b      = (const float*)d_in[12];
  const float* k_w      = (const float*)d_in[13];
  const float* k_b      = (const float*)d_in[14];
  const float* v_w      = (const float*)d_in[15];
  const float* v_b      = (const float*)d_in[16];
  const float* in_w     = (const float*)d_in[17];
  const float* in_b     = (const float*)d_in[18];
  const float* mo_w     = (const float*)d_in[19];
  const float* mo_b     = (const float*)d_in[20];
  const float* out_w    = (const float*)d_in[21];
  const float* out_b    = (const float*)d_in[22];
  const float* ln_g     = (const float*)d_in[23];
  const float* ln_beta  = (const float*)d_in[24];
  const int*   adjacency= (const int*)d_in[25];

  unsigned short* wsb = (unsigned short*)d_ws;
  float* wsf = (float*)((char*)d_ws + 106496);

  precompute_kernel<<<241, 256, 0, stream>>>(
      conv1_w, conv2_w, pm1_w, pm1_b, pm2_w, q_w, q_b, k_w, k_b, v_w, v_b,
      in_w, in_b, mo_w, out_w, pattern, points, adjacency, wsb, wsf);

  fused_kernel<<<2048, 512, 0, stream>>>(
      x, wsb, wsf, conv1_b, conv2_b, pm2_b, mo_b, out_b, ln_g, ln_beta,
      (float*)d_out);
}

// Round 4
// 167.673 us; speedup vs baseline: 1.2278x; 1.2278x over previous
//
#include <hip/hip_runtime.h>
#include <math.h>

using bf16x8 = __attribute__((ext_vector_type(8))) __bf16;
using f32x4  = __attribute__((ext_vector_type(4))) float;

#if __has_builtin(__builtin_amdgcn_exp2f)
#define EXP2F(x) __builtin_amdgcn_exp2f(x)
#else
#define EXP2F(x) exp2f(x)
#endif

__device__ __forceinline__ unsigned short f2bf(float f) {
  unsigned u = __float_as_uint(f);
  unsigned r = u + 0x7fffu + ((u >> 16) & 1u);
  return (unsigned short)(r >> 16);
}

// HW packed f32->bf16 (RNE, same rounding as f2bf). No builtin on gfx950 -> asm.
__device__ __forceinline__ unsigned cvt_pk_bf16(float a, float b) {
  unsigned r;
  asm("v_cvt_pk_bf16_f32 %0, %1, %2" : "=v"(r) : "v"(a), "v"(b));
  return r;
}
__device__ __forceinline__ uint2 pk4(float a, float b, float c, float d) {
  uint2 r; r.x = cvt_pk_bf16(a, b); r.y = cvt_pk_bf16(c, d); return r;
}

__device__ __forceinline__ f32x4 mfma16(uint4 a, uint4 b, f32x4 c) {
  return __builtin_amdgcn_mfma_f32_16x16x32_bf16(
      __builtin_bit_cast(bf16x8, a), __builtin_bit_cast(bf16x8, b), c, 0, 0, 0);
}
__device__ __forceinline__ float swz_xor16(float v) {
  return __int_as_float(__builtin_amdgcn_ds_swizzle(__float_as_int(v), 0x401F));
}

// B-fragment swizzled layout for mfma_f32_16x16x32_bf16:
// element (k, n) -> chunk index (((n>>4)*2 + (k>>5))*64 + ((k>>3)&3)*16 + (n&15))*8 + (k&7)
#define FRAG_OFF(k, n) (((((n) >> 4) * 2 + ((k) >> 5)) * 64 + (((k) >> 3) & 3) * 16 + ((n) & 15)) * 8 + ((k) & 7))

// attention score prescale: (1/sqrt(8)) * log2(e) folded into AQ/qb2
#define ATT_C 0.51006997f

// ---------------- precompute: bf16 weights + algebraic folds -> d_ws ----------------
// wsb (ushort): W1[3][4096]@0  W2[3][4096]@12288  PM1A@24576  PM2@28672
//               AQ@32768  AK@36864  AV@40960  MO@45056  OUT@49152
// wsf (float):  Cpat[4096]@0  geoT[4096]@4096  qb2@8192 kb2@8256 vb2@8320
__global__ void precompute_kernel(
    const float* __restrict__ conv1_w, const float* __restrict__ conv2_w,
    const float* __restrict__ pm1_w, const float* __restrict__ pm1_b,
    const float* __restrict__ pm2_w,
    const float* __restrict__ q_w, const float* __restrict__ q_b,
    const float* __restrict__ k_w, const float* __restrict__ k_b,
    const float* __restrict__ v_w, const float* __restrict__ v_b,
    const float* __restrict__ in_w, const float* __restrict__ in_b,
    const float* __restrict__ mo_w, const float* __restrict__ out_w,
    const float* __restrict__ pattern, const float* __restrict__ points,
    const int* __restrict__ adjacency,
    unsigned short* __restrict__ wsb, float* __restrict__ wsf) {
  int idx = blockIdx.x * 256 + threadIdx.x;
  if (idx < 12288) {                       // W1_t[oc][c] = conv1_w[oc][c][t]
    int t = idx >> 12, rem = idx & 4095;
    int oc = rem >> 6, c = rem & 63;
    wsb[idx] = f2bf(conv1_w[(oc * 64 + c) * 3 + t]);
  } else if (idx < 24576) {                // W2_t block-diagonal dense
    int i2 = idx - 12288;
    int t = i2 >> 12, rem = i2 & 4095;
    int oc = rem >> 6, ci = rem & 63;
    float v = ((ci >> 4) == (oc >> 4)) ? conv2_w[(oc * 16 + (ci & 15)) * 3 + t] : 0.0f;
    wsb[idx] = f2bf(v);
  } else if (idx < 28672) {                // PM1A = pm1_w[:, :64]
    int rem = idx - 24576;
    wsb[idx] = f2bf(pm1_w[(rem >> 6) * 80 + (rem & 63)]);
  } else if (idx < 32768) {                // PM2
    wsb[idx] = f2bf(pm2_w[idx - 28672]);
  } else if (idx < 36864) {                // AQ = (wq @ q_w) * ATT_C
    int rem = idx - 32768; int c = rem >> 6, k = rem & 63;
    float s = 0.f;
    #pragma unroll 8
    for (int j = 0; j < 64; ++j) s += in_w[c * 64 + j] * q_w[j * 64 + k];
    wsb[idx] = f2bf(s * ATT_C);
  } else if (idx < 40960) {                // AK = wk @ k_w
    int rem = idx - 36864; int c = rem >> 6, k = rem & 63;
    float s = 0.f;
    #pragma unroll 8
    for (int j = 0; j < 64; ++j) s += in_w[(64 + c) * 64 + j] * k_w[j * 64 + k];
    wsb[idx] = f2bf(s);
  } else if (idx < 45056) {                // AV = wv @ v_w
    int rem = idx - 40960; int c = rem >> 6, k = rem & 63;
    float s = 0.f;
    #pragma unroll 8
    for (int j = 0; j < 64; ++j) s += in_w[(128 + c) * 64 + j] * v_w[j * 64 + k];
    wsb[idx] = f2bf(s);
  } else if (idx < 49152) {                // MO
    wsb[idx] = f2bf(mo_w[idx - 45056]);
  } else if (idx < 53248) {                // OUT
    wsb[idx] = f2bf(out_w[idx - 49152]);
  } else if (idx < 57344) {                // Cpat[c][n] = pm1_w[:,64:] @ pat^T + pm1_b
    int rem = idx - 53248; int c = rem >> 6, n = rem & 63;
    float s = pm1_b[c];
    #pragma unroll
    for (int cp = 0; cp < 16; ++cp) s += pm1_w[c * 80 + 64 + cp] * pattern[n * 16 + cp];
    wsf[rem] = s;
  } else if (idx < 61440) {                // geoT[c][n] = geo[n][c]
    int rem = idx - 57344; int c = rem >> 6, n = rem & 63;
    float dd = 1e-12f;
    #pragma unroll
    for (int i = 0; i < 3; ++i) { float d = points[n * 3 + i] - points[c * 3 + i]; dd += d * d; }
    float dist = sqrtf(dd);
    wsf[4096 + rem] = (adjacency[n * 64 + c] > 0) ? 0.5f : (-0.1f / (1.0f + dist));
  } else if (idx < 61632) {                // fused qkv biases (q scaled by ATT_C)
    int rem = idx - 61440; int which = rem >> 6, c = rem & 63;
    if (which == 0) {
      float s = in_b[c];
      for (int j = 0; j < 64; ++j) s += in_w[c * 64 + j] * q_b[j];
      wsf[8192 + c] = s * ATT_C;
    } else if (which == 1) {
      float s = in_b[64 + c];
      for (int j = 0; j < 64; ++j) s += in_w[(64 + c) * 64 + j] * k_b[j];
      wsf[8256 + c] = s;
    } else {
      float s = in_b[128 + c];
      for (int j = 0; j < 64; ++j) s += in_w[(128 + c) * 64 + j] * v_b[j];
      wsf[8320 + c] = s;
    }
  }
}

// per-wave 64x64x64 GEMM: acc[nt] over rows c in [16w, 16w+16)
__device__ __forceinline__ void gemm64(const unsigned short* __restrict__ Wg,
                                       const unsigned short* Bf,
                                       int w, int lane, f32x4 acc[4]) {
  const int l15 = lane & 15, lq = lane >> 4;
  #pragma unroll
  for (int s = 0; s < 2; ++s) {
    bf16x8 a = *reinterpret_cast<const bf16x8*>(Wg + (16 * w + l15) * 64 + s * 32 + lq * 8);
    #pragma unroll
    for (int nt = 0; nt < 4; ++nt) {
      bf16x8 bb = *reinterpret_cast<const bf16x8*>(Bf + ((nt * 2 + s) * 64 + lane) * 8);
      acc[nt] = __builtin_amdgcn_mfma_f32_16x16x32_bf16(a, bb, acc[nt], 0, 0, 0);
    }
  }
}

// LDS pool 35840 B (shorts idx unless noted), phase-overlaid:
//  SLOT_A @0     (8KB):  XF(0-1) PIF(2-3) PFF(4-5) CTXF(6-7) HNF(8-9)
//  SLOT_B @4096  (9216B): Y1F(1-2) T1F(3-4) Q[n][72](5-6)
//  KBASE  @8704  (9216B): K[n][72](5-6a)  P scratch low (6b)
//  VBASE  @13312 (9216B): zero-guard(ph1-2) V[c][72](5-6a) P scratch high (6b)
//                         LN scratch(8)
//  P scratch (6b): 4 waves x 2 buffers x 1152 shorts = 9216 shorts spanning
//                  KBASE..pool end (K and V both dead after 6a preload)
//  H32 f32 idx 2048, stride 65 (7-8): overlays SLOT_B+KBASE (Q,K dead)
#define SLOT_B 4096
#define KBASE  8704
#define VBASE  13312
#define H32F   2048   /* f32 idx */
#define LNS    6656   /* f32 idx */

__global__ __launch_bounds__(256, 4) void fused_kernel(
    const float* __restrict__ x,
    const unsigned short* __restrict__ wsb, const float* __restrict__ wsf,
    const float* __restrict__ conv1_b, const float* __restrict__ conv2_b,
    const float* __restrict__ pm2_b, const float* __restrict__ mo_b,
    const float* __restrict__ out_b, const float* __restrict__ ln_g,
    const float* __restrict__ ln_beta, float* __restrict__ out) {
  __shared__ __align__(16) unsigned char smem_raw[35840];
  unsigned short* S16 = reinterpret_cast<unsigned short*>(smem_raw);
  float* S32 = reinterpret_cast<float*>(smem_raw);

  const int tid = threadIdx.x;
  const int b = blockIdx.x;
  const int lane = tid & 63;
  const int w = tid >> 6;
  const int l15 = lane & 15;
  const int lq = lane >> 4;
  const int c0 = 16 * w + lq * 4;   // D-frag row base for this lane
  f32x4 pfs[4];                     // pf residual, D-layout, ph4 -> ph7

  // ---------- Phase 0: zero-guard + stage x -> XF ----------
  // Wave w owns rows c in [16w, 16w+16), column n = lane (coalesced 256B loads).
  if (tid < 8) S16[VBASE + tid] = 0;   // 16B zero chunk for OOB shifted reads
  {
    const float* xb = x + b * 4096 + w * 16 * 64 + lane;
    float v[16];
    #pragma unroll
    for (int j = 0; j < 16; ++j) v[j] = xb[j * 64];
    #pragma unroll
    for (int g = 0; g < 2; ++g) {
      uint4 u;
      u.x = cvt_pk_bf16(v[g * 8 + 0], v[g * 8 + 1]);
      u.y = cvt_pk_bf16(v[g * 8 + 2], v[g * 8 + 3]);
      u.z = cvt_pk_bf16(v[g * 8 + 4], v[g * 8 + 5]);
      u.w = cvt_pk_bf16(v[g * 8 + 6], v[g * 8 + 7]);
      *reinterpret_cast<uint4*>(S16 + FRAG_OFF(w * 16 + g * 8, lane)) = u;
    }
  }
  __syncthreads();

  // ---------- conv helper: sum_t W_t @ shift(src, t-1), with zero-guard ----------
  auto conv_pass = [&](const unsigned short* Wg, int srcBase, f32x4 acc[4]) {
    bf16x8 a6[3][2];
    #pragma unroll
    for (int t = 0; t < 3; ++t)
      #pragma unroll
      for (int s = 0; s < 2; ++s)
        a6[t][s] = *reinterpret_cast<const bf16x8*>(Wg + t * 4096 + (16 * w + l15) * 64 + s * 32 + lq * 8);
    #pragma unroll
    for (int nt = 0; nt < 4; ++nt) {
      #pragma unroll
      for (int t = 0; t < 3; ++t) {
        int np = nt * 16 + l15 + (t - 1);
        bool ok = (unsigned)np < 64u;
        int a = srcBase + (((np >> 4) * 2) * 64 + lq * 16 + (np & 15)) * 8;
        int A0 = ok ? a : VBASE;
        int A1 = ok ? (a + 512) : VBASE;
        bf16x8 b0 = *reinterpret_cast<const bf16x8*>(S16 + A0);
        bf16x8 b1 = *reinterpret_cast<const bf16x8*>(S16 + A1);
        acc[nt] = __builtin_amdgcn_mfma_f32_16x16x32_bf16(a6[t][0], b0, acc[nt], 0, 0, 0);
        acc[nt] = __builtin_amdgcn_mfma_f32_16x16x32_bf16(a6[t][1], b1, acc[nt], 0, 0, 0);
      }
    }
  };

  // ---------- Phase 1: conv1 -> Y1F @SLOT_B ----------
  {
    f32x4 acc[4] = {};
    conv_pass(wsb, 0, acc);
    float bia[4] = {conv1_b[c0], conv1_b[c0 + 1], conv1_b[c0 + 2], conv1_b[c0 + 3]};
    #pragma unroll
    for (int nt = 0; nt < 4; ++nt) {
      int n = nt * 16 + l15;
      uint2 u = pk4(fmaxf(acc[nt][0] + bia[0], 0.f), fmaxf(acc[nt][1] + bia[1], 0.f),
                    fmaxf(acc[nt][2] + bia[2], 0.f), fmaxf(acc[nt][3] + bia[3], 0.f));
      *reinterpret_cast<uint2*>(S16 + SLOT_B + FRAG_OFF(c0, n)) = u;
    }
  }
  __syncthreads();

  // ---------- Phase 2: conv2 -> PIF @SLOT_A ----------
  {
    f32x4 acc[4] = {};
    conv_pass(wsb + 12288, SLOT_B, acc);
    float bia[4] = {conv2_b[c0], conv2_b[c0 + 1], conv2_b[c0 + 2], conv2_b[c0 + 3]};
    #pragma unroll
    for (int nt = 0; nt < 4; ++nt) {
      int n = nt * 16 + l15;
      uint2 u = pk4(fmaxf(acc[nt][0] + bia[0], 0.f), fmaxf(acc[nt][1] + bia[1], 0.f),
                    fmaxf(acc[nt][2] + bia[2], 0.f), fmaxf(acc[nt][3] + bia[3], 0.f));
      *reinterpret_cast<uint2*>(S16 + FRAG_OFF(c0, n)) = u;
    }
  }
  __syncthreads();

  // ---------- Phase 3: pm1: relu(PM1A @ PIF + Cpat) -> T1F @SLOT_B ----------
  {
    f32x4 acc[4] = {};
    gemm64(wsb + 24576, S16, w, lane, acc);
    #pragma unroll
    for (int nt = 0; nt < 4; ++nt) {
      int n = nt * 16 + l15;
      uint2 u = pk4(fmaxf(acc[nt][0] + wsf[(c0 + 0) * 64 + n], 0.f),
                    fmaxf(acc[nt][1] + wsf[(c0 + 1) * 64 + n], 0.f),
                    fmaxf(acc[nt][2] + wsf[(c0 + 2) * 64 + n], 0.f),
                    fmaxf(acc[nt][3] + wsf[(c0 + 3) * 64 + n], 0.f));
      *reinterpret_cast<uint2*>(S16 + SLOT_B + FRAG_OFF(c0, n)) = u;
    }
  }
  __syncthreads();

  // ---------- Phase 4: pm2: PM2 @ T1F + b -> PFF @SLOT_A + pf regs ----------
  {
    f32x4 acc[4] = {};
    gemm64(wsb + 28672, S16 + SLOT_B, w, lane, acc);
    float bia[4] = {pm2_b[c0], pm2_b[c0 + 1], pm2_b[c0 + 2], pm2_b[c0 + 3]};
    #pragma unroll
    for (int nt = 0; nt < 4; ++nt) {
      int n = nt * 16 + l15;
      f32x4 v;
      #pragma unroll
      for (int r = 0; r < 4; ++r) v[r] = acc[nt][r] + bia[r];
      pfs[nt] = v;
      *reinterpret_cast<uint2*>(S16 + FRAG_OFF(c0, n)) = pk4(v[0], v[1], v[2], v[3]);
    }
  }
  __syncthreads();

  // ---------- Phase 5: Q@SLOT_B, K@KBASE (bf16 [n][72]); V@VBASE (bf16 [c][72]) ----------
  {
    f32x4 acc[4] = {};
    gemm64(wsb + 32768, S16, w, lane, acc);   // AQ (pre-scaled)
    #pragma unroll
    for (int nt = 0; nt < 4; ++nt) {
      int n = nt * 16 + l15;
      *reinterpret_cast<uint2*>(S16 + SLOT_B + n * 72 + c0) =
          pk4(acc[nt][0] + wsf[8192 + c0], acc[nt][1] + wsf[8192 + c0 + 1],
              acc[nt][2] + wsf[8192 + c0 + 2], acc[nt][3] + wsf[8192 + c0 + 3]);
    }
  }
  {
    f32x4 acc[4] = {};
    gemm64(wsb + 36864, S16, w, lane, acc);   // AK
    #pragma unroll
    for (int nt = 0; nt < 4; ++nt) {
      int n = nt * 16 + l15;
      *reinterpret_cast<uint2*>(S16 + KBASE + n * 72 + c0) =
          pk4(acc[nt][0] + wsf[8256 + c0], acc[nt][1] + wsf[8256 + c0 + 1],
              acc[nt][2] + wsf[8256 + c0 + 2], acc[nt][3] + wsf[8256 + c0 + 3]);
    }
  }
  {
    f32x4 acc[4] = {};
    gemm64(wsb + 40960, S16, w, lane, acc);   // AV -> [c][72] scatter
    #pragma unroll
    for (int nt = 0; nt < 4; ++nt) {
      int n = nt * 16 + l15;
      #pragma unroll
      for (int r = 0; r < 4; ++r)
        S16[VBASE + (c0 + r) * 72 + n] = f2bf(acc[nt][r] + wsf[8320 + c0 + r]);
    }
  }
  __syncthreads();

  // ---------- Phase 6: MFMA attention, software-pipelined chains ----------
  {
    const bool lq0 = (lq == 0);
    // 6a: preload V B-frags AND zero-masked K A-frags for BOTH heads.
    // (P scratch below overlays both the K and V regions, so every K/V read
    //  must complete before the barrier.)
    uint4 vb[2][2], ka[2][4];
    #pragma unroll
    for (int rr = 0; rr < 2; ++rr) {
      const int h = w + rr * 4;
      #pragma unroll
      for (int ks = 0; ks < 2; ++ks)
        vb[rr][ks] = *reinterpret_cast<const uint4*>(
            S16 + VBASE + (h * 8 + (l15 & 7)) * 72 + ks * 32 + lq * 8);
      #pragma unroll
      for (int mt = 0; mt < 4; ++mt) {
        uint4 t = *reinterpret_cast<const uint4*>(
            S16 + KBASE + (mt * 16 + l15) * 72 + h * 8);
        ka[rr][mt].x = lq0 ? t.x : 0u; ka[rr][mt].y = lq0 ? t.y : 0u;
        ka[rr][mt].z = lq0 ? t.z : 0u; ka[rr][mt].w = lq0 ? t.w : 0u;
      }
    }
    __syncthreads();   // all K/V reads done before P scratch overwrites them

    // 8 chains i = rr*4 + q (head h = w + rr*4, query quarter q).
    // TWO P buffers per wave, alternating by i&1, spanning dead K+V regions:
    //   Pb(i) = KBASE + (w*2 + (i&1))*1152   (4 waves x 2 x 1152 shorts = 9216)
    // stage A(i): qb load -> scores -> softmax -> pack -> P-write buf(i&1)
    // stage B(i): P-read buf(i&1) -> PV MFMA -> ctx scatter
    // Schedule A0 A1 B0 A2 B1 ... A7 B6 B7: A(i+1)'s independent work sits
    // between A(i)'s P-write and B(i)'s dependent P-read, breaking the
    // same-address write->read->MFMA serialization that capped MfmaUtil.
    auto stageA = [&](int i) {
      const int rr = i >> 2, q = i & 3;
      const int h = w + rr * 4;
      uint4 qb = *reinterpret_cast<const uint4*>(
          S16 + SLOT_B + (q * 16 + l15) * 72 + h * 8);
      qb.x = lq0 ? qb.x : 0u; qb.y = lq0 ? qb.y : 0u;
      qb.z = lq0 ? qb.z : 0u; qb.w = lq0 ? qb.w : 0u;
      f32x4 sc[4];
      #pragma unroll
      for (int mt = 0; mt < 4; ++mt) {
        f32x4 z = {0.f, 0.f, 0.f, 0.f};
        sc[mt] = mfma16(ka[rr][mt], qb, z);   // S[m][n=l15] in exp2 domain
      }
      // softmax denominator (no max pass; scores are small)
      float sum = 0.f;
      #pragma unroll
      for (int mt = 0; mt < 4; ++mt)
        #pragma unroll
        for (int r = 0; r < 4; ++r) {
          float e = EXP2F(sc[mt][r]);
          sc[mt][r] = e; sum += e;
        }
      sum += swz_xor16(sum);
      sum += __shfl_xor(sum, 32);
      float inv = __builtin_amdgcn_rcpf(sum);
      const int Pb = KBASE + (w * 2 + (i & 1)) * 1152;
      // normalized P -> bf16 (truncation via v_perm) -> scratch [n=l15][m]
      #pragma unroll
      for (int mt = 0; mt < 4; ++mt) {
        unsigned d0 = __builtin_amdgcn_perm(__float_as_uint(sc[mt][1] * inv),
                                            __float_as_uint(sc[mt][0] * inv), 0x07060302u);
        unsigned d1 = __builtin_amdgcn_perm(__float_as_uint(sc[mt][3] * inv),
                                            __float_as_uint(sc[mt][2] * inv), 0x07060302u);
        *reinterpret_cast<uint2*>(S16 + Pb + l15 * 72 + mt * 16 + lq * 4) =
            make_uint2(d0, d1);
      }
    };
    auto stageB = [&](int i) {
      const int rr = i >> 2, q = i & 3;
      const int Pb = KBASE + (w * 2 + (i & 1)) * 1152;
      // PV: ctx[n][d] = sum_m P[n][m] V[h*8+d][m]
      f32x4 ctx = {0.f, 0.f, 0.f, 0.f};
      #pragma unroll
      for (int ks = 0; ks < 2; ++ks) {
        uint4 pa = *reinterpret_cast<const uint4*>(
            S16 + Pb + l15 * 72 + ks * 32 + lq * 8);
        ctx = mfma16(pa, vb[rr][ks], ctx);
      }
      // scatter ctx (C-layout: n=q*16+lq*4+r, d=l15<8) into CTXF @SLOT_A
      if (l15 < 8) {
        const int kk = (w + rr * 4) * 8 + l15;
        #pragma unroll
        for (int r = 0; r < 4; ++r)
          S16[FRAG_OFF(kk, q * 16 + lq * 4 + r)] = f2bf(ctx[r]);
      }
    };
    stageA(0);
    #pragma unroll
    for (int i = 0; i < 8; ++i) {
      if (i < 7) stageA(i + 1);
      stageB(i);
    }
  }
  __syncthreads();

  // ---------- Phase 7: MO @ CTXF + mo_b + geoT + pf(regs) -> H32 (f32 stride 65) ----------
  {
    f32x4 acc[4] = {};
    gemm64(wsb + 45056, S16, w, lane, acc);
    #pragma unroll
    for (int nt = 0; nt < 4; ++nt) {
      int n = nt * 16 + l15;
      #pragma unroll
      for (int r = 0; r < 4; ++r) {
        int c = c0 + r;
        S32[H32F + c * 65 + n] = acc[nt][r] + mo_b[c] + wsf[4096 + c * 64 + n] + pfs[nt][r];
      }
    }
  }
  __syncthreads();

  // ---------- Phase 8: LayerNorm over channels (per column n) -> HNF @SLOT_A ----------
  {
    int n = tid & 63, qq = tid >> 6;
    float sum = 0.f, ssq = 0.f;
    #pragma unroll
    for (int j = 0; j < 16; ++j) {
      float v = S32[H32F + (qq * 16 + j) * 65 + n];
      sum += v; ssq += v * v;
    }
    S32[LNS + tid] = sum;
    S32[LNS + 256 + tid] = ssq;
    __syncthreads();
    if (tid < 64) {
      float s = S32[LNS + tid] + S32[LNS + 64 + tid] + S32[LNS + 128 + tid] + S32[LNS + 192 + tid];
      float ss = S32[LNS + 256 + tid] + S32[LNS + 320 + tid] + S32[LNS + 384 + tid] + S32[LNS + 448 + tid];
      float mu = s * (1.0f / 64.0f);
      float var = ss * (1.0f / 64.0f) - mu * mu;
      S32[LNS + 512 + tid] = mu;
      S32[LNS + 576 + tid] = rsqrtf(var + 1e-5f);
    }
    __syncthreads();
    float mu = S32[LNS + 512 + n], rs = S32[LNS + 576 + n];
    #pragma unroll
    for (int half = 0; half < 2; ++half) {
      int ch0 = qq * 16 + half * 8;
      float vv[8];
      #pragma unroll
      for (int jj = 0; jj < 8; ++jj) {
        int c = ch0 + jj;
        vv[jj] = (S32[H32F + c * 65 + n] - mu) * rs * ln_g[c] + ln_beta[c];
      }
      uint4 u;
      u.x = cvt_pk_bf16(vv[0], vv[1]);
      u.y = cvt_pk_bf16(vv[2], vv[3]);
      u.z = cvt_pk_bf16(vv[4], vv[5]);
      u.w = cvt_pk_bf16(vv[6], vv[7]);
      *reinterpret_cast<uint4*>(S16 + FRAG_OFF(ch0, n)) = u;
    }
  }
  __syncthreads();

  // ---------- Phase 9: OUT @ HNF + out_b -> global [b][c][n] ----------
  {
    f32x4 acc[4] = {};
    gemm64(wsb + 49152, S16, w, lane, acc);
    float* ob = out + b * 4096;
    float bia[4] = {out_b[c0], out_b[c0 + 1], out_b[c0 + 2], out_b[c0 + 3]};
    #pragma unroll
    for (int nt = 0; nt < 4; ++nt) {
      int n = nt * 16 + l15;
      #pragma unroll
      for (int r = 0; r < 4; ++r)
        ob[(c0 + r) * 64 + n] = acc[nt][r] + bia[r];
    }
  }
}

extern "C" void kernel_launch(void* const* d_in, const int* in_sizes, int n_in,
                              void* d_out, int out_size, void* d_ws, size_t ws_size,
                              hipStream_t stream) {
  const float* x        = (const float*)d_in[0];
  const float* points   = (const float*)d_in[1];
  const float* conv1_w  = (const float*)d_in[2];
  const float* conv1_b  = (const float*)d_in[3];
  const float* conv2_w  = (const float*)d_in[4];
  const float* conv2_b  = (const float*)d_in[5];
  const float* pattern  = (const float*)d_in[6];
  const float* pm1_w    = (const float*)d_in[7];
  const float* pm1_b    = (const float*)d_in[8];
  const float* pm2_w    = (const float*)d_in[9];
  const float* pm2_b    = (const float*)d_in[10];
  const float* q_w      = (const float*)d_in[11];
  const float* q_b      = (const float*)d_in[12];
  const float* k_w      = (const float*)d_in[13];
  const float* k_b      = (const float*)d_in[14];
  const float* v_w      = (const float*)d_in[15];
  const float* v_b      = (const float*)d_in[16];
  const float* in_w     = (const float*)d_in[17];
  const float* in_b     = (const float*)d_in[18];
  const float* mo_w     = (const float*)d_in[19];
  const float* mo_b     = (const float*)d_in[20];
  const float* out_w    = (const float*)d_in[21];
  const float* out_b    = (const float*)d_in[22];
  const float* ln_g     = (const float*)d_in[23];
  const float* ln_beta  = (const float*)d_in[24];
  const int*   adjacency= (const int*)d_in[25];

  unsigned short* wsb = (unsigned short*)d_ws;
  float* wsf = (float*)((char*)d_ws + 106496);

  precompute_kernel<<<241, 256, 0, stream>>>(
      conv1_w, conv2_w, pm1_w, pm1_b, pm2_w, q_w, q_b, k_w, k_b, v_w, v_b,
      in_w, in_b, mo_w, out_w, pattern, points, adjacency, wsb, wsf);

  fused_kernel<<<2048, 256, 0, stream>>>(
      x, wsb, wsf, conv1_b, conv2_b, pm2_b, mo_b, out_b, ln_g, ln_beta,
      (float*)d_out);
}

// Round 5
// 164.226 us; speedup vs baseline: 1.2535x; 1.0210x over previous
//
#include <hip/hip_runtime.h>
#include <math.h>

using bf16x8 = __attribute__((ext_vector_type(8))) __bf16;
using f32x4  = __attribute__((ext_vector_type(4))) float;

#if __has_builtin(__builtin_amdgcn_exp2f)
#define EXP2F(x) __builtin_amdgcn_exp2f(x)
#else
#define EXP2F(x) exp2f(x)
#endif

__device__ __forceinline__ unsigned short f2bf(float f) {
  unsigned u = __float_as_uint(f);
  unsigned r = u + 0x7fffu + ((u >> 16) & 1u);
  return (unsigned short)(r >> 16);
}

// HW packed f32->bf16 (RNE, same rounding as f2bf). No builtin on gfx950 -> asm.
__device__ __forceinline__ unsigned cvt_pk_bf16(float a, float b) {
  unsigned r;
  asm("v_cvt_pk_bf16_f32 %0, %1, %2" : "=v"(r) : "v"(a), "v"(b));
  return r;
}
__device__ __forceinline__ uint2 pk4(float a, float b, float c, float d) {
  uint2 r; r.x = cvt_pk_bf16(a, b); r.y = cvt_pk_bf16(c, d); return r;
}

__device__ __forceinline__ f32x4 mfma16(uint4 a, uint4 b, f32x4 c) {
  return __builtin_amdgcn_mfma_f32_16x16x32_bf16(
      __builtin_bit_cast(bf16x8, a), __builtin_bit_cast(bf16x8, b), c, 0, 0, 0);
}
__device__ __forceinline__ float swz_xor16(float v) {
  return __int_as_float(__builtin_amdgcn_ds_swizzle(__float_as_int(v), 0x401F));
}

// B-fragment swizzled layout for mfma_f32_16x16x32_bf16:
// element (k, n) -> chunk index (((n>>4)*2 + (k>>5))*64 + ((k>>3)&3)*16 + (n&15))*8 + (k&7)
#define FRAG_OFF(k, n) (((((n) >> 4) * 2 + ((k) >> 5)) * 64 + (((k) >> 3) & 3) * 16 + ((n) & 15)) * 8 + ((k) & 7))

// attention score prescale: (1/sqrt(8)) * log2(e) folded into AQ/qb2
#define ATT_C 0.51006997f

// ---------------- precompute: bf16 weights + algebraic folds -> d_ws ----------------
// wsb (ushort): W1[3][4096]@0  W2[3][4096]@12288  PM1A@24576  PM2@28672
//               AQ@32768  AK@36864  AV@40960  MO@45056  OUT@49152
// wsf (float):  CpatD[4096]@0 (per-thread D-frag order: [tid][nt*4+r])
//               geoD[4096]@4096 (same order)  qb2@8192 kb2@8256 vb2@8320
__global__ void precompute_kernel(
    const float* __restrict__ conv1_w, const float* __restrict__ conv2_w,
    const float* __restrict__ pm1_w, const float* __restrict__ pm1_b,
    const float* __restrict__ pm2_w,
    const float* __restrict__ q_w, const float* __restrict__ q_b,
    const float* __restrict__ k_w, const float* __restrict__ k_b,
    const float* __restrict__ v_w, const float* __restrict__ v_b,
    const float* __restrict__ in_w, const float* __restrict__ in_b,
    const float* __restrict__ mo_w, const float* __restrict__ out_w,
    const float* __restrict__ pattern, const float* __restrict__ points,
    const int* __restrict__ adjacency,
    unsigned short* __restrict__ wsb, float* __restrict__ wsf) {
  int idx = blockIdx.x * 256 + threadIdx.x;
  if (idx < 12288) {                       // W1_t[oc][c] = conv1_w[oc][c][t]
    int t = idx >> 12, rem = idx & 4095;
    int oc = rem >> 6, c = rem & 63;
    wsb[idx] = f2bf(conv1_w[(oc * 64 + c) * 3 + t]);
  } else if (idx < 24576) {                // W2_t block-diagonal dense
    int i2 = idx - 12288;
    int t = i2 >> 12, rem = i2 & 4095;
    int oc = rem >> 6, ci = rem & 63;
    float v = ((ci >> 4) == (oc >> 4)) ? conv2_w[(oc * 16 + (ci & 15)) * 3 + t] : 0.0f;
    wsb[idx] = f2bf(v);
  } else if (idx < 28672) {                // PM1A = pm1_w[:, :64]
    int rem = idx - 24576;
    wsb[idx] = f2bf(pm1_w[(rem >> 6) * 80 + (rem & 63)]);
  } else if (idx < 32768) {                // PM2
    wsb[idx] = f2bf(pm2_w[idx - 28672]);
  } else if (idx < 36864) {                // AQ = (wq @ q_w) * ATT_C
    int rem = idx - 32768; int c = rem >> 6, k = rem & 63;
    float s = 0.f;
    #pragma unroll 8
    for (int j = 0; j < 64; ++j) s += in_w[c * 64 + j] * q_w[j * 64 + k];
    wsb[idx] = f2bf(s * ATT_C);
  } else if (idx < 40960) {                // AK = wk @ k_w
    int rem = idx - 36864; int c = rem >> 6, k = rem & 63;
    float s = 0.f;
    #pragma unroll 8
    for (int j = 0; j < 64; ++j) s += in_w[(64 + c) * 64 + j] * k_w[j * 64 + k];
    wsb[idx] = f2bf(s);
  } else if (idx < 45056) {                // AV = wv @ v_w
    int rem = idx - 40960; int c = rem >> 6, k = rem & 63;
    float s = 0.f;
    #pragma unroll 8
    for (int j = 0; j < 64; ++j) s += in_w[(128 + c) * 64 + j] * v_w[j * 64 + k];
    wsb[idx] = f2bf(s);
  } else if (idx < 49152) {                // MO
    wsb[idx] = f2bf(mo_w[idx - 45056]);
  } else if (idx < 53248) {                // OUT
    wsb[idx] = f2bf(out_w[idx - 49152]);
  } else if (idx < 57344) {                // CpatD[t][j]: per-thread D-frag order
    int rem = idx - 53248; int t = rem >> 4, j = rem & 15;
    int wq = t >> 6, lq = (t >> 4) & 3, l15 = t & 15;
    int c = wq * 16 + lq * 4 + (j & 3);
    int n = (j >> 2) * 16 + l15;
    float s = pm1_b[c];
    #pragma unroll
    for (int cp = 0; cp < 16; ++cp) s += pm1_w[c * 80 + 64 + cp] * pattern[n * 16 + cp];
    wsf[rem] = s;
  } else if (idx < 61440) {                // geoD[t][j]: geo[n][c] in D-frag order
    int rem = idx - 57344; int t = rem >> 4, j = rem & 15;
    int wq = t >> 6, lq = (t >> 4) & 3, l15 = t & 15;
    int c = wq * 16 + lq * 4 + (j & 3);
    int n = (j >> 2) * 16 + l15;
    float dd = 1e-12f;
    #pragma unroll
    for (int i = 0; i < 3; ++i) { float d = points[n * 3 + i] - points[c * 3 + i]; dd += d * d; }
    float dist = sqrtf(dd);
    wsf[4096 + rem] = (adjacency[n * 64 + c] > 0) ? 0.5f : (-0.1f / (1.0f + dist));
  } else if (idx < 61632) {                // fused qkv biases (q scaled by ATT_C)
    int rem = idx - 61440; int which = rem >> 6, c = rem & 63;
    if (which == 0) {
      float s = in_b[c];
      for (int j = 0; j < 64; ++j) s += in_w[c * 64 + j] * q_b[j];
      wsf[8192 + c] = s * ATT_C;
    } else if (which == 1) {
      float s = in_b[64 + c];
      for (int j = 0; j < 64; ++j) s += in_w[(64 + c) * 64 + j] * k_b[j];
      wsf[8256 + c] = s;
    } else {
      float s = in_b[128 + c];
      for (int j = 0; j < 64; ++j) s += in_w[(128 + c) * 64 + j] * v_b[j];
      wsf[8320 + c] = s;
    }
  }
}

// per-wave 64x64x64 GEMM with PRELOADED A-fragments (weights already in regs)
__device__ __forceinline__ void gemm64r(const bf16x8 a[2], const unsigned short* Bf,
                                        int lane, f32x4 acc[4]) {
  #pragma unroll
  for (int s = 0; s < 2; ++s) {
    #pragma unroll
    for (int nt = 0; nt < 4; ++nt) {
      bf16x8 bb = *reinterpret_cast<const bf16x8*>(Bf + ((nt * 2 + s) * 64 + lane) * 8);
      acc[nt] = __builtin_amdgcn_mfma_f32_16x16x32_bf16(a[s], bb, acc[nt], 0, 0, 0);
    }
  }
}

// LDS pool 35840 B (shorts idx unless noted), phase-overlaid:
//  SLOT_A @0     (8KB):  XF(0-1) PIF(2-3) PFF(4-5) CTXF(6-7) HNF(8-9)
//  SLOT_B @4096  (9216B): Y1F(1-2) T1F(3-4) Q[n][72](5-6)
//  KBASE  @8704  (9216B): K[n][72](5-6a)  P scratch low (6b)
//  VBASE  @13312 (9216B): zero-guard(ph1-2) V[c][72](5-6a) P scratch high (6b)
//                         LN scratch(8)
//  P scratch (6b): 4 waves x 2 buffers x 1152 shorts spanning KBASE..pool end
//  H32 f32 idx 2048, stride 65 (7-8): overlays SLOT_B+KBASE (Q,K dead)
#define SLOT_B 4096
#define KBASE  8704
#define VBASE  13312
#define H32F   2048   /* f32 idx */
#define LNS    6656   /* f32 idx */

__global__ __launch_bounds__(256, 4) void fused_kernel(
    const float* __restrict__ x,
    const unsigned short* __restrict__ wsb, const float* __restrict__ wsf,
    const float* __restrict__ conv1_b, const float* __restrict__ conv2_b,
    const float* __restrict__ pm2_b, const float* __restrict__ mo_b,
    const float* __restrict__ out_b, const float* __restrict__ ln_g,
    const float* __restrict__ ln_beta, float* __restrict__ out) {
  __shared__ __align__(16) unsigned char smem_raw[35840];
  unsigned short* S16 = reinterpret_cast<unsigned short*>(smem_raw);
  float* S32 = reinterpret_cast<float*>(smem_raw);

  const int tid = threadIdx.x;
  const int b = blockIdx.x;
  const int lane = tid & 63;
  const int w = tid >> 6;
  const int l15 = lane & 15;
  const int lq = lane >> 4;
  const int c0 = 16 * w + lq * 4;   // D-frag row base for this lane
  f32x4 pfs[4];                     // pf residual, D-layout, ph4 -> ph7

  // prefetch helpers: weight A-frag for this wave's rows, table offset off
  auto ldw = [&](int off) -> bf16x8 {
    return *reinterpret_cast<const bf16x8*>(wsb + off + (16 * w + l15) * 64 + lq * 8);
  };

  // rotating prefetch registers (assigned before the barrier preceding use)
  bf16x8 a6[3][2];                  // conv weights (W1 then W2)
  bf16x8 pA[2], pB[2], pC[2];       // generic GEMM A-frag pairs
  f32x4 cp4[4], gd4[4];             // CpatD / geoD addends (per-thread contiguous)
  f32x4 bq4, bk4, bv4, mo_b4, ob4;  // prefetched biases

  // ---------- Phase 0: zero-guard + stage x -> XF; prefetch conv1 ----------
  if (tid < 8) S16[VBASE + tid] = 0;   // 16B zero chunk for OOB shifted reads
  {
    const float* xb = x + b * 4096 + w * 16 * 64 + lane;
    float v[16];
    #pragma unroll
    for (int j = 0; j < 16; ++j) v[j] = xb[j * 64];
    #pragma unroll
    for (int g = 0; g < 2; ++g) {
      uint4 u;
      u.x = cvt_pk_bf16(v[g * 8 + 0], v[g * 8 + 1]);
      u.y = cvt_pk_bf16(v[g * 8 + 2], v[g * 8 + 3]);
      u.z = cvt_pk_bf16(v[g * 8 + 4], v[g * 8 + 5]);
      u.w = cvt_pk_bf16(v[g * 8 + 6], v[g * 8 + 7]);
      *reinterpret_cast<uint4*>(S16 + FRAG_OFF(w * 16 + g * 8, lane)) = u;
    }
  }
  #pragma unroll
  for (int t = 0; t < 3; ++t) { a6[t][0] = ldw(t * 4096); a6[t][1] = ldw(t * 4096 + 32); }
  f32x4 c1b = *reinterpret_cast<const f32x4*>(conv1_b + c0);
  __syncthreads();

  // ---------- conv helper: sum_t W_t(regs) @ shift(src, t-1), zero-guard ----------
  auto conv_pass = [&](int srcBase, f32x4 acc[4]) {
    #pragma unroll
    for (int nt = 0; nt < 4; ++nt) {
      #pragma unroll
      for (int t = 0; t < 3; ++t) {
        int np = nt * 16 + l15 + (t - 1);
        bool ok = (unsigned)np < 64u;
        int a = srcBase + (((np >> 4) * 2) * 64 + lq * 16 + (np & 15)) * 8;
        int A0 = ok ? a : VBASE;
        int A1 = ok ? (a + 512) : VBASE;
        bf16x8 b0 = *reinterpret_cast<const bf16x8*>(S16 + A0);
        bf16x8 b1 = *reinterpret_cast<const bf16x8*>(S16 + A1);
        acc[nt] = __builtin_amdgcn_mfma_f32_16x16x32_bf16(a6[t][0], b0, acc[nt], 0, 0, 0);
        acc[nt] = __builtin_amdgcn_mfma_f32_16x16x32_bf16(a6[t][1], b1, acc[nt], 0, 0, 0);
      }
    }
  };

  // ---------- Phase 1: conv1 -> Y1F @SLOT_B; prefetch conv2 ----------
  {
    f32x4 acc[4] = {};
    conv_pass(0, acc);
    #pragma unroll
    for (int nt = 0; nt < 4; ++nt) {
      int n = nt * 16 + l15;
      uint2 u = pk4(fmaxf(acc[nt][0] + c1b[0], 0.f), fmaxf(acc[nt][1] + c1b[1], 0.f),
                    fmaxf(acc[nt][2] + c1b[2], 0.f), fmaxf(acc[nt][3] + c1b[3], 0.f));
      *reinterpret_cast<uint2*>(S16 + SLOT_B + FRAG_OFF(c0, n)) = u;
    }
  }
  #pragma unroll
  for (int t = 0; t < 3; ++t) { a6[t][0] = ldw(12288 + t * 4096); a6[t][1] = ldw(12288 + t * 4096 + 32); }
  f32x4 c2b = *reinterpret_cast<const f32x4*>(conv2_b + c0);
  __syncthreads();

  // ---------- Phase 2: conv2 -> PIF @SLOT_A; prefetch PM1A + CpatD ----------
  {
    f32x4 acc[4] = {};
    conv_pass(SLOT_B, acc);
    #pragma unroll
    for (int nt = 0; nt < 4; ++nt) {
      int n = nt * 16 + l15;
      uint2 u = pk4(fmaxf(acc[nt][0] + c2b[0], 0.f), fmaxf(acc[nt][1] + c2b[1], 0.f),
                    fmaxf(acc[nt][2] + c2b[2], 0.f), fmaxf(acc[nt][3] + c2b[3], 0.f));
      *reinterpret_cast<uint2*>(S16 + FRAG_OFF(c0, n)) = u;
    }
  }
  pA[0] = ldw(24576); pA[1] = ldw(24576 + 32);
  #pragma unroll
  for (int k2 = 0; k2 < 4; ++k2)
    cp4[k2] = *reinterpret_cast<const f32x4*>(wsf + tid * 16 + k2 * 4);
  __syncthreads();

  // ---------- Phase 3: pm1: relu(PM1A @ PIF + CpatD) -> T1F @SLOT_B; prefetch PM2 ----------
  {
    f32x4 acc[4] = {};
    gemm64r(pA, S16, lane, acc);
    #pragma unroll
    for (int nt = 0; nt < 4; ++nt) {
      int n = nt * 16 + l15;
      uint2 u = pk4(fmaxf(acc[nt][0] + cp4[nt][0], 0.f),
                    fmaxf(acc[nt][1] + cp4[nt][1], 0.f),
                    fmaxf(acc[nt][2] + cp4[nt][2], 0.f),
                    fmaxf(acc[nt][3] + cp4[nt][3], 0.f));
      *reinterpret_cast<uint2*>(S16 + SLOT_B + FRAG_OFF(c0, n)) = u;
    }
  }
  pA[0] = ldw(28672); pA[1] = ldw(28672 + 32);
  f32x4 p2b = *reinterpret_cast<const f32x4*>(pm2_b + c0);
  __syncthreads();

  // ---------- Phase 4: pm2 -> PFF @SLOT_A + pf regs; prefetch AQ/AK/AV + biases ----------
  {
    f32x4 acc[4] = {};
    gemm64r(pA, S16 + SLOT_B, lane, acc);
    #pragma unroll
    for (int nt = 0; nt < 4; ++nt) {
      int n = nt * 16 + l15;
      f32x4 v;
      #pragma unroll
      for (int r = 0; r < 4; ++r) v[r] = acc[nt][r] + p2b[r];
      pfs[nt] = v;
      *reinterpret_cast<uint2*>(S16 + FRAG_OFF(c0, n)) = pk4(v[0], v[1], v[2], v[3]);
    }
  }
  pA[0] = ldw(32768); pA[1] = ldw(32768 + 32);
  pB[0] = ldw(36864); pB[1] = ldw(36864 + 32);
  pC[0] = ldw(40960); pC[1] = ldw(40960 + 32);
  bq4 = *reinterpret_cast<const f32x4*>(wsf + 8192 + c0);
  bk4 = *reinterpret_cast<const f32x4*>(wsf + 8256 + c0);
  bv4 = *reinterpret_cast<const f32x4*>(wsf + 8320 + c0);
  __syncthreads();

  // ---------- Phase 5: Q@SLOT_B, K@KBASE (bf16 [n][72]); V@VBASE (bf16 [c][72]) ----------
  {
    f32x4 acc[4] = {};
    gemm64r(pA, S16, lane, acc);   // AQ (pre-scaled)
    #pragma unroll
    for (int nt = 0; nt < 4; ++nt) {
      int n = nt * 16 + l15;
      *reinterpret_cast<uint2*>(S16 + SLOT_B + n * 72 + c0) =
          pk4(acc[nt][0] + bq4[0], acc[nt][1] + bq4[1],
              acc[nt][2] + bq4[2], acc[nt][3] + bq4[3]);
    }
  }
  {
    f32x4 acc[4] = {};
    gemm64r(pB, S16, lane, acc);   // AK
    #pragma unroll
    for (int nt = 0; nt < 4; ++nt) {
      int n = nt * 16 + l15;
      *reinterpret_cast<uint2*>(S16 + KBASE + n * 72 + c0) =
          pk4(acc[nt][0] + bk4[0], acc[nt][1] + bk4[1],
              acc[nt][2] + bk4[2], acc[nt][3] + bk4[3]);
    }
  }
  {
    f32x4 acc[4] = {};
    gemm64r(pC, S16, lane, acc);   // AV -> [c][72] scatter
    #pragma unroll
    for (int nt = 0; nt < 4; ++nt) {
      int n = nt * 16 + l15;
      #pragma unroll
      for (int r = 0; r < 4; ++r)
        S16[VBASE + (c0 + r) * 72 + n] = f2bf(acc[nt][r] + bv4[r]);
    }
  }
  __syncthreads();

  // ---------- Phase 6: MFMA attention, software-pipelined chains ----------
  {
    const bool lq0 = (lq == 0);
    // 6a: preload V B-frags AND zero-masked K A-frags for BOTH heads.
    uint4 vb[2][2], ka[2][4];
    #pragma unroll
    for (int rr = 0; rr < 2; ++rr) {
      const int h = w + rr * 4;
      #pragma unroll
      for (int ks = 0; ks < 2; ++ks)
        vb[rr][ks] = *reinterpret_cast<const uint4*>(
            S16 + VBASE + (h * 8 + (l15 & 7)) * 72 + ks * 32 + lq * 8);
      #pragma unroll
      for (int mt = 0; mt < 4; ++mt) {
        uint4 t = *reinterpret_cast<const uint4*>(
            S16 + KBASE + (mt * 16 + l15) * 72 + h * 8);
        ka[rr][mt].x = lq0 ? t.x : 0u; ka[rr][mt].y = lq0 ? t.y : 0u;
        ka[rr][mt].z = lq0 ? t.z : 0u; ka[rr][mt].w = lq0 ? t.w : 0u;
      }
    }
    __syncthreads();   // all K/V reads done before P scratch overwrites them

    // 8 chains i = rr*4 + q; double-buffered P scratch; A(i+1) overlaps B(i).
    auto stageA = [&](int i) {
      const int rr = i >> 2, q = i & 3;
      const int h = w + rr * 4;
      uint4 qb = *reinterpret_cast<const uint4*>(
          S16 + SLOT_B + (q * 16 + l15) * 72 + h * 8);
      qb.x = lq0 ? qb.x : 0u; qb.y = lq0 ? qb.y : 0u;
      qb.z = lq0 ? qb.z : 0u; qb.w = lq0 ? qb.w : 0u;
      f32x4 sc[4];
      #pragma unroll
      for (int mt = 0; mt < 4; ++mt) {
        f32x4 z = {0.f, 0.f, 0.f, 0.f};
        sc[mt] = mfma16(ka[rr][mt], qb, z);   // S[m][n=l15] in exp2 domain
      }
      float sum = 0.f;
      #pragma unroll
      for (int mt = 0; mt < 4; ++mt)
        #pragma unroll
        for (int r = 0; r < 4; ++r) {
          float e = EXP2F(sc[mt][r]);
          sc[mt][r] = e; sum += e;
        }
      sum += swz_xor16(sum);
      sum += __shfl_xor(sum, 32);
      float inv = __builtin_amdgcn_rcpf(sum);
      const int Pb = KBASE + (w * 2 + (i & 1)) * 1152;
      #pragma unroll
      for (int mt = 0; mt < 4; ++mt) {
        unsigned d0 = __builtin_amdgcn_perm(__float_as_uint(sc[mt][1] * inv),
                                            __float_as_uint(sc[mt][0] * inv), 0x07060302u);
        unsigned d1 = __builtin_amdgcn_perm(__float_as_uint(sc[mt][3] * inv),
                                            __float_as_uint(sc[mt][2] * inv), 0x07060302u);
        *reinterpret_cast<uint2*>(S16 + Pb + l15 * 72 + mt * 16 + lq * 4) =
            make_uint2(d0, d1);
      }
    };
    auto stageB = [&](int i) {
      const int rr = i >> 2, q = i & 3;
      const int Pb = KBASE + (w * 2 + (i & 1)) * 1152;
      f32x4 ctx = {0.f, 0.f, 0.f, 0.f};
      #pragma unroll
      for (int ks = 0; ks < 2; ++ks) {
        uint4 pa = *reinterpret_cast<const uint4*>(
            S16 + Pb + l15 * 72 + ks * 32 + lq * 8);
        ctx = mfma16(pa, vb[rr][ks], ctx);
      }
      if (l15 < 8) {
        const int kk = (w + rr * 4) * 8 + l15;
        #pragma unroll
        for (int r = 0; r < 4; ++r)
          S16[FRAG_OFF(kk, q * 16 + lq * 4 + r)] = f2bf(ctx[r]);
      }
    };
    stageA(0);
    #pragma unroll
    for (int i = 0; i < 8; ++i) {
      if (i < 7) stageA(i + 1);
      stageB(i);
    }
  }
  // prefetch MO frags + mo_b + geoD (issued before the barrier; used in ph7)
  pA[0] = ldw(45056); pA[1] = ldw(45056 + 32);
  mo_b4 = *reinterpret_cast<const f32x4*>(mo_b + c0);
  #pragma unroll
  for (int k2 = 0; k2 < 4; ++k2)
    gd4[k2] = *reinterpret_cast<const f32x4*>(wsf + 4096 + tid * 16 + k2 * 4);
  __syncthreads();

  // ---------- Phase 7: MO @ CTXF + mo_b + geoD + pf(regs) -> H32 (f32 stride 65) ----------
  {
    f32x4 acc[4] = {};
    gemm64r(pA, S16, lane, acc);
    #pragma unroll
    for (int nt = 0; nt < 4; ++nt) {
      int n = nt * 16 + l15;
      #pragma unroll
      for (int r = 0; r < 4; ++r) {
        int c = c0 + r;
        S32[H32F + c * 65 + n] = acc[nt][r] + mo_b4[r] + gd4[nt][r] + pfs[nt][r];
      }
    }
  }
  __syncthreads();

  // ---------- Phase 8: LayerNorm over channels (per column n) -> HNF @SLOT_A ----------
  {
    int n = tid & 63, qq = tid >> 6;
    // vectorized gamma/beta loads (issued at phase start, used after barriers)
    f32x4 g0 = *reinterpret_cast<const f32x4*>(ln_g + qq * 16);
    f32x4 g1 = *reinterpret_cast<const f32x4*>(ln_g + qq * 16 + 4);
    f32x4 g2 = *reinterpret_cast<const f32x4*>(ln_g + qq * 16 + 8);
    f32x4 g3 = *reinterpret_cast<const f32x4*>(ln_g + qq * 16 + 12);
    f32x4 e0 = *reinterpret_cast<const f32x4*>(ln_beta + qq * 16);
    f32x4 e1 = *reinterpret_cast<const f32x4*>(ln_beta + qq * 16 + 4);
    f32x4 e2 = *reinterpret_cast<const f32x4*>(ln_beta + qq * 16 + 8);
    f32x4 e3 = *reinterpret_cast<const f32x4*>(ln_beta + qq * 16 + 12);
    float sum = 0.f, ssq = 0.f;
    #pragma unroll
    for (int j = 0; j < 16; ++j) {
      float v = S32[H32F + (qq * 16 + j) * 65 + n];
      sum += v; ssq += v * v;
    }
    S32[LNS + tid] = sum;
    S32[LNS + 256 + tid] = ssq;
    __syncthreads();
    if (tid < 64) {
      float s = S32[LNS + tid] + S32[LNS + 64 + tid] + S32[LNS + 128 + tid] + S32[LNS + 192 + tid];
      float ss = S32[LNS + 256 + tid] + S32[LNS + 320 + tid] + S32[LNS + 384 + tid] + S32[LNS + 448 + tid];
      float mu = s * (1.0f / 64.0f);
      float var = ss * (1.0f / 64.0f) - mu * mu;
      S32[LNS + 512 + tid] = mu;
      S32[LNS + 576 + tid] = rsqrtf(var + 1e-5f);
    }
    __syncthreads();
    float mu = S32[LNS + 512 + n], rs = S32[LNS + 576 + n];
    float gg[16] = {g0[0],g0[1],g0[2],g0[3], g1[0],g1[1],g1[2],g1[3],
                    g2[0],g2[1],g2[2],g2[3], g3[0],g3[1],g3[2],g3[3]};
    float ee[16] = {e0[0],e0[1],e0[2],e0[3], e1[0],e1[1],e1[2],e1[3],
                    e2[0],e2[1],e2[2],e2[3], e3[0],e3[1],e3[2],e3[3]};
    #pragma unroll
    for (int half = 0; half < 2; ++half) {
      int ch0 = qq * 16 + half * 8;
      float vv[8];
      #pragma unroll
      for (int jj = 0; jj < 8; ++jj) {
        int c = ch0 + jj;
        vv[jj] = (S32[H32F + c * 65 + n] - mu) * rs * gg[half * 8 + jj] + ee[half * 8 + jj];
      }
      uint4 u;
      u.x = cvt_pk_bf16(vv[0], vv[1]);
      u.y = cvt_pk_bf16(vv[2], vv[3]);
      u.z = cvt_pk_bf16(vv[4], vv[5]);
      u.w = cvt_pk_bf16(vv[6], vv[7]);
      *reinterpret_cast<uint4*>(S16 + FRAG_OFF(ch0, n)) = u;
    }
  }
  // prefetch OUT frags + out_b (used in ph9)
  pA[0] = ldw(49152); pA[1] = ldw(49152 + 32);
  ob4 = *reinterpret_cast<const f32x4*>(out_b + c0);
  __syncthreads();

  // ---------- Phase 9: OUT @ HNF + out_b -> global [b][c][n] ----------
  {
    f32x4 acc[4] = {};
    gemm64r(pA, S16, lane, acc);
    float* ob = out + b * 4096;
    #pragma unroll
    for (int nt = 0; nt < 4; ++nt) {
      int n = nt * 16 + l15;
      #pragma unroll
      for (int r = 0; r < 4; ++r)
        ob[(c0 + r) * 64 + n] = acc[nt][r] + ob4[r];
    }
  }
}

extern "C" void kernel_launch(void* const* d_in, const int* in_sizes, int n_in,
                              void* d_out, int out_size, void* d_ws, size_t ws_size,
                              hipStream_t stream) {
  const float* x        = (const float*)d_in[0];
  const float* points   = (const float*)d_in[1];
  const float* conv1_w  = (const float*)d_in[2];
  const float* conv1_b  = (const float*)d_in[3];
  const float* conv2_w  = (const float*)d_in[4];
  const float* conv2_b  = (const float*)d_in[5];
  const float* pattern  = (const float*)d_in[6];
  const float* pm1_w    = (const float*)d_in[7];
  const float* pm1_b    = (const float*)d_in[8];
  const float* pm2_w    = (const float*)d_in[9];
  const float* pm2_b    = (const float*)d_in[10];
  const float* q_w      = (const float*)d_in[11];
  const float* q_b      = (const float*)d_in[12];
  const float* k_w      = (const float*)d_in[13];
  const float* k_b      = (const float*)d_in[14];
  const float* v_w      = (const float*)d_in[15];
  const float* v_b      = (const float*)d_in[16];
  const float* in_w     = (const float*)d_in[17];
  const float* in_b     = (const float*)d_in[18];
  const float* mo_w     = (const float*)d_in[19];
  const float* mo_b     = (const float*)d_in[20];
  const float* out_w    = (const float*)d_in[21];
  const float* out_b    = (const float*)d_in[22];
  const float* ln_g     = (const float*)d_in[23];
  const float* ln_beta  = (const float*)d_in[24];
  const int*   adjacency= (const int*)d_in[25];

  unsigned short* wsb = (unsigned short*)d_ws;
  float* wsf = (float*)((char*)d_ws + 106496);

  precompute_kernel<<<241, 256, 0, stream>>>(
      conv1_w, conv2_w, pm1_w, pm1_b, pm2_w, q_w, q_b, k_w, k_b, v_w, v_b,
      in_w, in_b, mo_w, out_w, pattern, points, adjacency, wsb, wsf);

  fused_kernel<<<2048, 256, 0, stream>>>(
      x, wsb, wsf, conv1_b, conv2_b, pm2_b, mo_b, out_b, ln_g, ln_beta,
      (float*)d_out);
}